// Round 1
// baseline (734.401 us; speedup 1.0000x reference)
//
#include <hip/hip_runtime.h>

#define NN   4096
#define MREC 4000
#define MSUB 20000
#define MGM  10

// One block per row; first-occurrence argmax over M contiguous floats.
__global__ __launch_bounds__(256) void argmax_rows_kernel(
    const float* __restrict__ mat, int M, int* __restrict__ out)
{
    const int row = blockIdx.x;
    const float* __restrict__ rowp = mat + (size_t)row * (size_t)M;
    const int tid = threadIdx.x;

    float best = -__builtin_inff();
    int   bidx = 0;
    // Each thread scans ascending indices -> "if >" keeps first occurrence.
    for (int c = tid * 4; c < M; c += 256 * 4) {
        const float4 v = *reinterpret_cast<const float4*>(rowp + c);
        if (v.x > best) { best = v.x; bidx = c;     }
        if (v.y > best) { best = v.y; bidx = c + 1; }
        if (v.z > best) { best = v.z; bidx = c + 2; }
        if (v.w > best) { best = v.w; bidx = c + 3; }
    }
    // Wave-64 reduction with min-index tie-break.
    #pragma unroll
    for (int off = 32; off > 0; off >>= 1) {
        float ov = __shfl_down(best, off, 64);
        int   oi = __shfl_down(bidx, off, 64);
        if (ov > best || (ov == best && oi < bidx)) { best = ov; bidx = oi; }
    }
    __shared__ float svals[4];
    __shared__ int   sidxs[4];
    const int wave = tid >> 6;
    if ((tid & 63) == 0) { svals[wave] = best; sidxs[wave] = bidx; }
    __syncthreads();
    if (tid == 0) {
        #pragma unroll
        for (int w = 1; w < 4; ++w) {
            if (svals[w] > best || (svals[w] == best && sidxs[w] < bidx)) {
                best = svals[w]; bidx = sidxs[w];
            }
        }
        out[row] = bidx;
    }
}

// Per-i gathers: p_self, Thaptic, Tprefer.
__global__ __launch_bounds__(256) void gather_kernel(
    const int* __restrict__ ri, const int* __restrict__ si,
    const int* __restrict__ vid,
    const float* __restrict__ pref,      // (P, N)
    const float* __restrict__ structure, // (MSUB, MREC)
    float* __restrict__ p_self,
    float* __restrict__ out)             // [0:N)=Tprefer, [2N:3N)=Thaptic
{
    const int i = blockIdx.x * blockDim.x + threadIdx.x;
    if (i >= NN) return;
    const int r = ri[i];
    const int s = si[i];
    const float ps = pref[(size_t)s * NN + i];
    p_self[i] = ps;
    out[2 * NN + i] = structure[(size_t)s * MREC + r];          // Thaptic
    const int v = vid[MGM + r];                                 // vid_s[ri[i]]
    out[i] = ps - pref[(size_t)v * NN + i];                     // Tprefer
}

// Tsocial[i] = sum_{j != i, si[j]==si[i]} min(p_self[i], p_self[j])
__global__ __launch_bounds__(256) void tsocial_kernel(
    const int* __restrict__ si, const float* __restrict__ p_self,
    float* __restrict__ tsocial)
{
    const int i   = blockIdx.x;
    const int tid = threadIdx.x;
    const int   my_s = si[i];
    const float my_p = p_self[i];
    float acc = 0.f;
    for (int j = tid; j < NN; j += 256) {
        if (j != i && si[j] == my_s) acc += fminf(my_p, p_self[j]);
    }
    #pragma unroll
    for (int off = 32; off > 0; off >>= 1) acc += __shfl_down(acc, off, 64);
    __shared__ float ss[4];
    if ((tid & 63) == 0) ss[tid >> 6] = acc;
    __syncthreads();
    if (tid == 0) tsocial[i] = ss[0] + ss[1] + ss[2] + ss[3];
}

extern "C" void kernel_launch(void* const* d_in, const int* in_sizes, int n_in,
                              void* d_out, int out_size, void* d_ws, size_t ws_size,
                              hipStream_t stream)
{
    const float* Rec  = (const float*)d_in[0];  // (N, M_REC)
    const float* Sub  = (const float*)d_in[1];  // (N, M_SUB)
    // d_in[2] ItemGroups_m   — unused by reference
    const int*   Vid  = (const int*)d_in[3];    // (MGM + M_REC,)
    // d_in[4..7] VUU/KUU/Vscore/Kscore — unused
    const float* pref = (const float*)d_in[8];  // (P, N)
    const float* str  = (const float*)d_in[9];  // (M_SUB, M_REC)
    float* out = (float*)d_out;                 // [Tprefer | Tsocial | Thaptic]

    int*   ri     = (int*)d_ws;
    int*   si     = ri + NN;
    float* p_self = (float*)(si + NN);

    argmax_rows_kernel<<<NN, 256, 0, stream>>>(Rec, MREC, ri);
    argmax_rows_kernel<<<NN, 256, 0, stream>>>(Sub, MSUB, si);
    gather_kernel<<<(NN + 255) / 256, 256, 0, stream>>>(ri, si, Vid, pref, str, p_self, out);
    tsocial_kernel<<<NN, 256, 0, stream>>>(si, p_self, out + NN);
}